// Round 22
// baseline (197.326 us; speedup 1.0000x reference)
//
#include <hip/hip_runtime.h>
#include <hip/hip_bf16.h>

typedef float f32x4 __attribute__((ext_vector_type(4)));
typedef short s16x8 __attribute__((ext_vector_type(8)));
typedef short s16x4 __attribute__((ext_vector_type(4)));
typedef unsigned short u16;

#define H_ 16
#define E_ 64
#define D_ 1024
#define L_ 2048
#define SCL2E 0.18033688011f   // (1/sqrt(64)) * log2(e)

__device__ __forceinline__ u16 f2bf(float f) {
  union { float f; unsigned u; } v; v.f = f;
  unsigned u = v.u;
  u += 0x7fffu + ((u >> 16) & 1u);   // round-to-nearest-even
  return (u16)(u >> 16);
}

// pack 2 f32 -> 2 bf16 in one u32 (lo=a, hi=b). NON-volatile: schedulable.
__device__ __forceinline__ unsigned pkbf(float a, float b) {
  unsigned r;
  asm("v_cvt_pk_bf16_f32 %0, %1, %2" : "=v"(r) : "v"(a), "v"(b));
  return r;
}

// async global->LDS, 16B per lane. lds base must be wave-uniform; HW adds lane*16.
__device__ __forceinline__ void gld16(const u16* g, u16* l) {
  __builtin_amdgcn_global_load_lds((const __attribute__((address_space(1))) void*)g,
                                   (__attribute__((address_space(3))) void*)l, 16, 0, 0);
}

// single-launch f32->bf16 convert: 3 activations (4096 blocks each) then
// 4 weights (512 blocks each); Wq pre-scaled by SCL2E (softmax scale fold).
__global__ __launch_bounds__(256) void cvtall(const float* __restrict__ q,
                                              const float* __restrict__ k,
                                              const float* __restrict__ v,
                                              const float* __restrict__ w0,
                                              const float* __restrict__ w1,
                                              const float* __restrict__ w2,
                                              const float* __restrict__ w3,
                                              u16* __restrict__ qd,
                                              u16* __restrict__ kd,
                                              u16* __restrict__ vd,
                                              u16* __restrict__ d0,
                                              u16* __restrict__ d1,
                                              u16* __restrict__ d2,
                                              u16* __restrict__ d3) {
  const int b = blockIdx.x;
  const float* src; u16* dst; float s = 1.0f; size_t off;
  if (b < 12288) {
    const int y = b >> 12, bx = b & 4095;
    src = y == 0 ? q : (y == 1 ? k : v);
    dst = y == 0 ? qd : (y == 1 ? kd : vd);
    off = ((size_t)bx * 256 + threadIdx.x) * 8;
  } else {
    const int b2 = b - 12288, y = b2 >> 9, bx = b2 & 511;
    src = y == 0 ? w0 : (y == 1 ? w1 : (y == 2 ? w2 : w3));
    dst = y == 0 ? d0 : (y == 1 ? d1 : (y == 2 ? d2 : d3));
    if (y == 0) s = SCL2E;
    off = ((size_t)bx * 256 + threadIdx.x) * 8;
  }
  const f32x4 a = *(const f32x4*)(src + off);
  const f32x4 c = *(const f32x4*)(src + off + 4);
  s16x8 r;
#pragma unroll
  for (int j = 0; j < 4; ++j) { r[j] = (short)f2bf(a[j] * s); r[j + 4] = (short)f2bf(c[j] * s); }
  *(s16x8*)(dst + off) = r;
}

// ---------- bf16 GEMM: BK=64, PREFETCHED LDS double-buffer (T3 min-2-phase) --
template<int PERMUTE>
__global__ __launch_bounds__(256) void gemm_lds(const u16* __restrict__ A,
                                                const u16* __restrict__ W,
                                                const float* __restrict__ bias,
                                                void* __restrict__ outp,
                                                int M, int N, int K, float bsc)
{
  __shared__ __align__(16) u16 As[2][128][64];   // 32KB
  __shared__ __align__(16) u16 Bs[2][128][64];   // 32KB
  const int tid = threadIdx.x;
  const int m0 = blockIdx.y * 128, n0 = blockIdx.x * 128;
  const int w = tid >> 6, lane = tid & 63, g = lane >> 4, li = lane & 15;
  const int wr = w >> 1, wc = w & 1;

  int sOff[4];
#pragma unroll
  for (int j = 0; j < 4; ++j) {
    const int s = (w * 4 + j) * 64 + lane;
    const int row = s >> 3, c8 = s & 7;
    sOff[j] = row * K + ((c8 ^ (row & 7)) * 8);
  }

  f32x4 acc[4][4];
#pragma unroll
  for (int i = 0; i < 4; ++i)
#pragma unroll
    for (int j = 0; j < 4; ++j) acc[i][j] = (f32x4){0.f, 0.f, 0.f, 0.f};

  const u16* Abase = A + (size_t)m0 * K;
  const u16* Wbase = W + (size_t)n0 * K;
  const int swz = li & 7;

  auto STAGE = [&](int k0, int bf) {
#pragma unroll
    for (int j = 0; j < 4; ++j) {
      gld16(Abase + k0 + sOff[j], &As[bf][(w * 4 + j) * 8][0]);
      gld16(Wbase + k0 + sOff[j], &Bs[bf][(w * 4 + j) * 8][0]);
    }
  };

  STAGE(0, 0);
  __syncthreads();
  int buf = 0;
  for (int k0 = 0; k0 < K; k0 += 64) {
    if (k0 + 64 < K) STAGE(k0 + 64, buf ^ 1);   // in flight during compute

    s16x8 a[2][4], b[2][4];
#pragma unroll
    for (int kk = 0; kk < 2; ++kk) {
      const int cg = ((kk * 4 + g) ^ swz) * 8;
#pragma unroll
      for (int mi = 0; mi < 4; ++mi) a[kk][mi] = *(const s16x8*)&As[buf][wr * 64 + mi * 16 + li][cg];
#pragma unroll
      for (int ni = 0; ni < 4; ++ni) b[kk][ni] = *(const s16x8*)&Bs[buf][wc * 64 + ni * 16 + li][cg];
    }
#pragma unroll
    for (int kk = 0; kk < 2; ++kk)
#pragma unroll
      for (int mi = 0; mi < 4; ++mi)
#pragma unroll
        for (int ni = 0; ni < 4; ++ni)
          acc[mi][ni] = __builtin_amdgcn_mfma_f32_16x16x32_bf16(a[kk][mi], b[kk][ni], acc[mi][ni], 0, 0, 0);

    __syncthreads();   // buf read done + stage(k+1) landed
    buf ^= 1;
  }

#pragma unroll
  for (int mi = 0; mi < 4; ++mi) {
#pragma unroll
    for (int ni = 0; ni < 4; ++ni) {
      const int row = m0 + wr * 64 + mi * 16 + g * 4;
      const int col = n0 + wc * 64 + ni * 16 + li;
      const float bv = bias[col] * bsc;
      if (PERMUTE == 2) {
        s16x4 pk;
#pragma unroll
        for (int r = 0; r < 4; ++r) pk[r] = (short)f2bf(acc[mi][ni][r] + bv);
        const int bb = row >> 11, lq = row & (L_ - 1);
        const int hh = col >> 6, e = col & (E_ - 1);
        *(s16x4*)&((u16*)outp)[(((size_t)bb * H_ + hh) * E_ + e) * L_ + lq] = pk;
      } else {
#pragma unroll
        for (int r = 0; r < 4; ++r) {
          const float v = acc[mi][ni][r] + bv;
          const int rr = row + r;
          if (PERMUTE == 1) {
            const int bb = rr >> 11, lq = rr & (L_ - 1);
            const int hh = col >> 6, e = col & (E_ - 1);
            ((u16*)outp)[(((size_t)bb * H_ + hh) * L_ + lq) * E_ + e] = f2bf(v);
          } else {
            ((float*)outp)[(size_t)rr * N + col] = v;
          }
        }
      }
    }
  }
}

// ---------- fallback GEMM (reg-staged, f32 A converted on the fly) ------------
template<int A_BF16, int PERMUTE>
__global__ __launch_bounds__(256) void gemm_bt(const void* __restrict__ Aptr,
                                               const float* __restrict__ W,
                                               const float* __restrict__ bias,
                                               void* __restrict__ outp,
                                               int M, int N, int K, float osc)
{
  __shared__ __align__(16) short As[2][128][40];
  __shared__ __align__(16) short Bs[2][128][40];
  const int tid = threadIdx.x;
  const int m0 = blockIdx.y * 128, n0 = blockIdx.x * 128;
  const int w = tid >> 6, lane = tid & 63, g = lane >> 4, li = lane & 15;
  const int wr = w >> 1, wc = w & 1;

  f32x4 acc[4][4];
#pragma unroll
  for (int i = 0; i < 4; ++i)
#pragma unroll
    for (int j = 0; j < 4; ++j) acc[i][j] = (f32x4){0.f, 0.f, 0.f, 0.f};

  f32x4 ra0[2], ra1[2];
  s16x8 rab[2];
  f32x4 rb0[2], rb1[2];

  auto LOAD = [&](int k0) {
#pragma unroll
    for (int p = 0; p < 2; ++p) {
      const int c = p * 256 + tid, row = c >> 2, kc = (c & 3) * 8;
      if (A_BF16) {
        rab[p] = *(const s16x8*)((const u16*)Aptr + (size_t)(m0 + row) * K + k0 + kc);
      } else {
        const float* ap = (const float*)Aptr + (size_t)(m0 + row) * K + k0 + kc;
        ra0[p] = *(const f32x4*)ap; ra1[p] = *(const f32x4*)(ap + 4);
      }
      const float* wp = W + (size_t)(n0 + row) * K + k0 + kc;
      rb0[p] = *(const f32x4*)wp; rb1[p] = *(const f32x4*)(wp + 4);
    }
  };
  auto WRITE = [&](int buf) {
#pragma unroll
    for (int p = 0; p < 2; ++p) {
      const int c = p * 256 + tid, row = c >> 2, kc = (c & 3) * 8;
      if (A_BF16) {
        *(s16x8*)&As[buf][row][kc] = rab[p];
      } else {
        s16x8 r;
#pragma unroll
        for (int j = 0; j < 4; ++j) { r[j] = (short)f2bf(ra0[p][j]); r[j + 4] = (short)f2bf(ra1[p][j]); }
        *(s16x8*)&As[buf][row][kc] = r;
      }
      s16x8 rb;
#pragma unroll
      for (int j = 0; j < 4; ++j) { rb[j] = (short)f2bf(rb0[p][j]); rb[j + 4] = (short)f2bf(rb1[p][j]); }
      *(s16x8*)&Bs[buf][row][kc] = rb;
    }
  };

  LOAD(0); WRITE(0);
  __syncthreads();
  int cur = 0;
  for (int k0 = 0; k0 < K; k0 += 32) {
    const bool more = (k0 + 32 < K);
    if (more) LOAD(k0 + 32);

    s16x8 a[4], b[4];
#pragma unroll
    for (int mi = 0; mi < 4; ++mi) a[mi] = *(const s16x8*)&As[cur][wr * 64 + mi * 16 + li][g * 8];
#pragma unroll
    for (int ni = 0; ni < 4; ++ni) b[ni] = *(const s16x8*)&Bs[cur][wc * 64 + ni * 16 + li][g * 8];
#pragma unroll
    for (int mi = 0; mi < 4; ++mi)
#pragma unroll
      for (int ni = 0; ni < 4; ++ni)
        acc[mi][ni] = __builtin_amdgcn_mfma_f32_16x16x32_bf16(a[mi], b[ni], acc[mi][ni], 0, 0, 0);

    if (more) { WRITE(cur ^ 1); __syncthreads(); }
    cur ^= 1;
  }

#pragma unroll
  for (int mi = 0; mi < 4; ++mi) {
#pragma unroll
    for (int ni = 0; ni < 4; ++ni) {
      const int row = m0 + wr * 64 + mi * 16 + g * 4;
      const int col = n0 + wc * 64 + ni * 16 + li;
      const float bv = bias[col];
      if (PERMUTE == 2) {
        s16x4 pk;
#pragma unroll
        for (int r = 0; r < 4; ++r) pk[r] = (short)f2bf((acc[mi][ni][r] + bv) * osc);
        const int bb = row >> 11, lq = row & (L_ - 1);
        const int hh = col >> 6, e = col & (E_ - 1);
        *(s16x4*)&((u16*)outp)[(((size_t)bb * H_ + hh) * E_ + e) * L_ + lq] = pk;
      } else {
#pragma unroll
        for (int r = 0; r < 4; ++r) {
          const float v = (acc[mi][ni][r] + bv) * osc;
          const int rr = row + r;
          if (PERMUTE == 1) {
            const int bb = rr >> 11, lq = rr & (L_ - 1);
            const int hh = col >> 6, e = col & (E_ - 1);
            ((u16*)outp)[(((size_t)bb * H_ + hh) * L_ + lq) * E_ + e] = f2bf(v);
          } else {
            ((float*)outp)[(size_t)rr * N + col] = v;
          }
        }
      }
    }
  }
}

// Flash attention, causal. Grid: 1024 (1D). Block: 256 = 4 waves, QBLK=128,
// each wave owns 32 q-rows (two 16-row halves A/B). Per iteration a wave
// reads K/V fragments from LDS ONCE and runs QK/softmax/PV TWICE -> aggregate
// LDS-read traffic halves vs R21 (the measured bottleneck). XCD-grouped bh;
// longest q-tiles first. Lazy defer-max; l reduce hoisted to epilogue.
__global__ __launch_bounds__(256) void attn_kernel(const u16* __restrict__ qp,
                                                   const u16* __restrict__ kp,
                                                   const u16* __restrict__ vtp,
                                                   u16* __restrict__ op)
{
  __shared__ __align__(16) u16 Ks[2][4096];   // 8KB per buf
  __shared__ __align__(16) u16 Vs[2][4096];
  const int tid = threadIdx.x;
  const unsigned wgid = blockIdx.x;
  const int bh = (wgid & 7) * 8 + ((wgid >> 3) & 7);   // XCD c owns bh in [8c,8c+8)
  const int qb = 15 - (int)(wgid >> 6);                // 128-row q tile, longest first
  const int w = tid >> 6, lane = tid & 63, g = lane >> 4, li = lane & 15;
  const size_t base  = (size_t)bh * L_ * E_;
  const size_t baseT = (size_t)bh * E_ * L_;
  const int bb = bh >> 4, hh = bh & 15;
  const int qbase = qb * 128;
  const int nt = 2 * qb + 2;                  // 64-wide KV tiles this block needs
  const int rowA = qbase + w * 32 + li;       // half A q-row
  const int rowB = rowA + 16;                 // half B q-row

  const u16* qrA = qp + base + (size_t)rowA * E_;
  const s16x8 qaA0 = *(const s16x8*)(qrA + g * 8);
  const s16x8 qaA1 = *(const s16x8*)(qrA + 32 + g * 8);
  const u16* qrB = qp + base + (size_t)rowB * E_;
  const s16x8 qaB0 = *(const s16x8*)(qrB + g * 8);
  const s16x8 qaB1 = *(const s16x8*)(qrB + 32 + g * 8);

  f32x4 oA[4], oB[4];
  float mA = -1e30f, lA = 0.f, mB = -1e30f, lB = 0.f;   // per-lane partials
#pragma unroll
  for (int nc = 0; nc < 4; ++nc) { oA[nc] = (f32x4){0.f,0.f,0.f,0.f}; oB[nc] = (f32x4){0.f,0.f,0.f,0.f}; }

  // staging: 4 waves x 2 chunks of 1KB each for K and V. Pre-swizzled source.
  int kSrc[2], vSrc[2];
#pragma unroll
  for (int j = 0; j < 2; ++j) {
    const int s = (w * 2 + j) * 64 + lane;
    const int row = s >> 3;
    const int c8 = (s & 7) ^ ((row & 3) | (((row >> 3) & 1) << 2));
    kSrc[j] = row * E_ + c8 * 8;
    vSrc[j] = row * L_ + c8 * 8;   // row = e for V^T
  }
  auto stage = [&](int t, int buf) {
    const int kvb = t * 64;
#pragma unroll
    for (int j = 0; j < 2; ++j) {
      gld16(kp + base + (size_t)kvb * E_ + kSrc[j], &Ks[buf][(w * 2 + j) * 512]);
      gld16(vtp + baseT + kvb + vSrc[j],            &Vs[buf][(w * 2 + j) * 512]);
    }
  };

  // fragment read offsets (u16 index into 4096-elem buffer)
  const int swzk = li & 7;
  const int swzv = (li & 3) | (((li >> 3) & 1) << 2);
  int kRd[8], vRd[8];
#pragma unroll
  for (int inst = 0; inst < 4; ++inst) {
    const int bs = (32 * (inst >> 1) + 4 * (inst & 1) + 8 * (li >> 2) + (li & 3)) * 8;
    kRd[inst * 2]     = (bs + (g ^ swzk)) * 8;
    kRd[inst * 2 + 1] = (bs + ((g + 4) ^ swzk)) * 8;
  }
#pragma unroll
  for (int nc = 0; nc < 4; ++nc) {
    const int es = (nc * 16 + li) * 8;
    vRd[nc * 2]     = (es + (g ^ swzv)) * 8;
    vRd[nc * 2 + 1] = (es + ((g + 4) ^ swzv)) * 8;
  }

  // one half: QK -> mask -> lazy-defer-max softmax -> PV (all in registers)
  auto half = [&](const s16x8* kf, const s16x8* vf, int t,
                  const s16x8& q0, const s16x8& q1, int qrow,
                  f32x4* o, float& m_run, float& l_run) {
    f32x4 p[4];
#pragma unroll
    for (int inst = 0; inst < 4; ++inst) {
      f32x4 sf = (f32x4){0.f, 0.f, 0.f, 0.f};
      sf = __builtin_amdgcn_mfma_f32_16x16x32_bf16(kf[inst * 2],     q0, sf, 0, 0, 0);
      sf = __builtin_amdgcn_mfma_f32_16x16x32_bf16(kf[inst * 2 + 1], q1, sf, 0, 0, 0);
      p[inst] = sf;   // log2-domain (scale folded into Q)
    }
    if (t >= 2 * qb) {   // diagonal region: causal mask (k > q -> -inf)
      const int kvb = t * 64;
#pragma unroll
      for (int inst = 0; inst < 4; ++inst)
#pragma unroll
        for (int r = 0; r < 4; ++r)
          if (kvb + 32 * (inst >> 1) + 8 * g + 4 * (inst & 1) + r > qrow) p[inst][r] = -1e30f;
    }
    {
      float m0_ = fmaxf(fmaxf(p[0][0], p[0][1]), fmaxf(p[0][2], p[0][3]));
      float m1_ = fmaxf(fmaxf(p[1][0], p[1][1]), fmaxf(p[1][2], p[1][3]));
      float m2_ = fmaxf(fmaxf(p[2][0], p[2][1]), fmaxf(p[2][2], p[2][3]));
      float m3_ = fmaxf(fmaxf(p[3][0], p[3][1]), fmaxf(p[3][2], p[3][3]));
      const float mx16 = fmaxf(fmaxf(m0_, m1_), fmaxf(m2_, m3_));
      if (__any(mx16 > m_run + 8.0f)) {       // rare after t=0; always at t=0
        float mx = fmaxf(mx16, __shfl_xor(mx16, 16));
        mx = fmaxf(mx, __shfl_xor(mx, 32));
        const float mn = fmaxf(m_run, mx);
        const float alpha = __builtin_amdgcn_exp2f(m_run - mn);
        m_run = mn;
        l_run *= alpha;
#pragma unroll
        for (int nc = 0; nc < 4; ++nc)
#pragma unroll
          for (int r = 0; r < 4; ++r) o[nc][r] *= alpha;
      }
    }
    unsigned pk[8];
    float rs = 0.f;
#pragma unroll
    for (int inst = 0; inst < 4; ++inst) {
      const float e0 = __builtin_amdgcn_exp2f(p[inst][0] - m_run);
      const float e1 = __builtin_amdgcn_exp2f(p[inst][1] - m_run);
      const float e2 = __builtin_amdgcn_exp2f(p[inst][2] - m_run);
      const float e3 = __builtin_amdgcn_exp2f(p[inst][3] - m_run);
      rs += (e0 + e1) + (e2 + e3);
      pk[inst * 2]     = pkbf(e0, e1);
      pk[inst * 2 + 1] = pkbf(e2, e3);
    }
    l_run += rs;                               // per-lane partial; reduced in epilogue
    union { s16x8 v; unsigned u[4]; } A0, A1;
    A0.u[0] = pk[0]; A0.u[1] = pk[1]; A0.u[2] = pk[2]; A0.u[3] = pk[3];
    A1.u[0] = pk[4]; A1.u[1] = pk[5]; A1.u[2] = pk[6]; A1.u[3] = pk[7];
#pragma unroll
    for (int nc = 0; nc < 4; ++nc) {
      o[nc] = __builtin_amdgcn_mfma_f32_16x16x32_bf16(vf[nc * 2],     A0.v, o[nc], 0, 0, 0);
      o[nc] = __builtin_amdgcn_mfma_f32_16x16x32_bf16(vf[nc * 2 + 1], A1.v, o[nc], 0, 0, 0);
    }
  };

  stage(0, 0);
  __syncthreads();
  int buf = 0;
  for (int t = 0; t < nt; ++t) {
    const bool more = (t + 1 < nt);
    if (more) stage(t + 1, buf ^ 1);          // async into other buffer

    s16x8 kf[8], vf[8];                        // read ONCE, used by both halves
#pragma unroll
    for (int i = 0; i < 8; ++i) kf[i] = *(const s16x8*)&Ks[buf][kRd[i]];
#pragma unroll
    for (int i = 0; i < 8; ++i) vf[i] = *(const s16x8*)&Vs[buf][vRd[i]];

    half(kf, vf, t, qaA0, qaA1, rowA, oA, mA, lA);
    half(kf, vf, t, qaB0, qaB1, rowB, oB, mB, lB);

    if (more) __syncthreads();                 // drains stage(t+1); buf reuse safe
    buf ^= 1;
  }

  // epilogue: final cross-lane l reduce (linear; alphas uniform per row)
  auto epi = [&](const f32x4* o, float l_run, int qrow) {
    float lsum = l_run;
    lsum += __shfl_xor(lsum, 16);
    lsum += __shfl_xor(lsum, 32);
    const float inv = 1.0f / lsum;
    u16* orow = op + ((size_t)bb * L_ + qrow) * D_ + hh * E_;
#pragma unroll
    for (int nc = 0; nc < 4; ++nc) {
      union { s16x4 v; unsigned u[2]; } P;
      P.u[0] = pkbf(o[nc][0] * inv, o[nc][1] * inv);
      P.u[1] = pkbf(o[nc][2] * inv, o[nc][3] * inv);
      *(s16x4*)&orow[nc * 16 + g * 4] = P.v;
    }
  };
  epi(oA, lA, rowA);
  epi(oB, lB, rowB);
}

extern "C" void kernel_launch(void* const* d_in, const int* in_sizes, int n_in,
                              void* d_out, int out_size, void* d_ws, size_t ws_size,
                              hipStream_t stream) {
  const float* queries = (const float*)d_in[0];
  const float* keys    = (const float*)d_in[1];
  const float* values  = (const float*)d_in[2];
  // d_in[3] = attn_mask: exact causal triu(k=1), applied analytically.
  const float* Wq = (const float*)d_in[4];
  const float* bq = (const float*)d_in[5];
  const float* Wk = (const float*)d_in[6];
  const float* bk = (const float*)d_in[7];
  const float* Wv = (const float*)d_in[8];
  const float* bv = (const float*)d_in[9];
  const float* Wo = (const float*)d_in[10];
  const float* bo = (const float*)d_in[11];

  const size_t MD = (size_t)8192 * 1024;   // activation elems
  const size_t WN = (size_t)1024 * 1024;   // weight elems
  u16* qbuf = (u16*)d_ws;
  u16* kbuf = qbuf + MD;
  u16* vbuf = kbuf + MD;
  u16* abuf = vbuf + MD;

  dim3 blk(256);
  dim3 ggrid(8, 64);

  const size_t need = (4 * MD + 4 * WN) * sizeof(u16);
  if (ws_size >= need) {
    u16* qcv = abuf;           // aliases consumed in order V -> K -> Q -> attn
    u16* kcv = qbuf;
    u16* vcv = kbuf;
    u16* wqb = abuf + MD;
    u16* wkb = wqb + WN;
    u16* wvb = wkb + WN;
    u16* wob = wvb + WN;

    cvtall<<<dim3(14336), blk, 0, stream>>>(queries, keys, values, Wq, Wk, Wv, Wo,
                                            qcv, kcv, vcv, wqb, wkb, wvb, wob);

    gemm_lds<2><<<ggrid, blk, 0, stream>>>(vcv, wvb, bv, vbuf, 8192, 1024, 1024, 1.0f);
    gemm_lds<1><<<ggrid, blk, 0, stream>>>(kcv, wkb, bk, kbuf, 8192, 1024, 1024, 1.0f);
    gemm_lds<1><<<ggrid, blk, 0, stream>>>(qcv, wqb, bq, qbuf, 8192, 1024, 1024, SCL2E);
    attn_kernel<<<dim3(1024), blk, 0, stream>>>(qbuf, kbuf, vbuf, abuf);
    gemm_lds<0><<<ggrid, blk, 0, stream>>>(abuf, wob, bo, d_out, 8192, 1024, 1024, 1.0f);
  } else {
    gemm_bt<0, 1><<<ggrid, blk, 0, stream>>>(queries, Wq, bq, qbuf, 8192, 1024, 1024, SCL2E);
    gemm_bt<0, 1><<<ggrid, blk, 0, stream>>>(keys,    Wk, bk, kbuf, 8192, 1024, 1024, 1.0f);
    gemm_bt<0, 2><<<ggrid, blk, 0, stream>>>(values,  Wv, bv, vbuf, 8192, 1024, 1024, 1.0f);
    attn_kernel<<<dim3(1024), blk, 0, stream>>>(qbuf, kbuf, vbuf, abuf);
    gemm_bt<1, 0><<<ggrid, blk, 0, stream>>>(abuf, Wo, bo, d_out, 8192, 1024, 1024, 1.0f);
  }
}

// Round 23
// 186.525 us; speedup vs baseline: 1.0579x; 1.0579x over previous
//
#include <hip/hip_runtime.h>
#include <hip/hip_bf16.h>

typedef float f32x4 __attribute__((ext_vector_type(4)));
typedef short s16x8 __attribute__((ext_vector_type(8)));
typedef short s16x4 __attribute__((ext_vector_type(4)));
typedef unsigned short u16;

#define H_ 16
#define E_ 64
#define D_ 1024
#define L_ 2048
#define SCL2E 0.18033688011f   // (1/sqrt(64)) * log2(e)

__device__ __forceinline__ u16 f2bf(float f) {
  union { float f; unsigned u; } v; v.f = f;
  unsigned u = v.u;
  u += 0x7fffu + ((u >> 16) & 1u);   // round-to-nearest-even
  return (u16)(u >> 16);
}

// pack 2 f32 -> 2 bf16 in one u32 (lo=a, hi=b). NON-volatile: schedulable.
__device__ __forceinline__ unsigned pkbf(float a, float b) {
  unsigned r;
  asm("v_cvt_pk_bf16_f32 %0, %1, %2" : "=v"(r) : "v"(a), "v"(b));
  return r;
}

// async global->LDS, 16B per lane. lds base must be wave-uniform; HW adds lane*16.
__device__ __forceinline__ void gld16(const u16* g, u16* l) {
  __builtin_amdgcn_global_load_lds((const __attribute__((address_space(1))) void*)g,
                                   (__attribute__((address_space(3))) void*)l, 16, 0, 0);
}

// single-launch f32->bf16 convert: 3 activations (4096 blocks each) then
// 4 weights (512 blocks each); Wq pre-scaled by SCL2E (softmax scale fold).
__global__ __launch_bounds__(256) void cvtall(const float* __restrict__ q,
                                              const float* __restrict__ k,
                                              const float* __restrict__ v,
                                              const float* __restrict__ w0,
                                              const float* __restrict__ w1,
                                              const float* __restrict__ w2,
                                              const float* __restrict__ w3,
                                              u16* __restrict__ qd,
                                              u16* __restrict__ kd,
                                              u16* __restrict__ vd,
                                              u16* __restrict__ d0,
                                              u16* __restrict__ d1,
                                              u16* __restrict__ d2,
                                              u16* __restrict__ d3) {
  const int b = blockIdx.x;
  const float* src; u16* dst; float s = 1.0f; size_t off;
  if (b < 12288) {
    const int y = b >> 12, bx = b & 4095;
    src = y == 0 ? q : (y == 1 ? k : v);
    dst = y == 0 ? qd : (y == 1 ? kd : vd);
    off = ((size_t)bx * 256 + threadIdx.x) * 8;
  } else {
    const int b2 = b - 12288, y = b2 >> 9, bx = b2 & 511;
    src = y == 0 ? w0 : (y == 1 ? w1 : (y == 2 ? w2 : w3));
    dst = y == 0 ? d0 : (y == 1 ? d1 : (y == 2 ? d2 : d3));
    if (y == 0) s = SCL2E;
    off = ((size_t)bx * 256 + threadIdx.x) * 8;
  }
  const f32x4 a = *(const f32x4*)(src + off);
  const f32x4 c = *(const f32x4*)(src + off + 4);
  s16x8 r;
#pragma unroll
  for (int j = 0; j < 4; ++j) { r[j] = (short)f2bf(a[j] * s); r[j + 4] = (short)f2bf(c[j] * s); }
  *(s16x8*)(dst + off) = r;
}

// ---------- shared GEMM inner loop (BK=64, prefetched LDS dbuf, swizzled) ----
// Writes acc for a 128x128 tile of A*W^T. Returns via reference arrays.
template<typename EPIL>
__device__ __forceinline__ void gemm_core(const u16* __restrict__ A,
                                          const u16* __restrict__ W,
                                          int m0, int n0, int K,
                                          u16 (*As)[128][64], u16 (*Bs)[128][64],
                                          EPIL&& epil) {
  const int tid = threadIdx.x;
  const int w = tid >> 6, lane = tid & 63, g = lane >> 4, li = lane & 15;
  const int wr = w >> 1, wc = w & 1;

  int sOff[4];
#pragma unroll
  for (int j = 0; j < 4; ++j) {
    const int s = (w * 4 + j) * 64 + lane;
    const int row = s >> 3, c8 = s & 7;
    sOff[j] = row * K + ((c8 ^ (row & 7)) * 8);
  }

  f32x4 acc[4][4];
#pragma unroll
  for (int i = 0; i < 4; ++i)
#pragma unroll
    for (int j = 0; j < 4; ++j) acc[i][j] = (f32x4){0.f, 0.f, 0.f, 0.f};

  const u16* Abase = A + (size_t)m0 * K;
  const u16* Wbase = W + (size_t)n0 * K;
  const int swz = li & 7;

  auto STAGE = [&](int k0, int bf) {
#pragma unroll
    for (int j = 0; j < 4; ++j) {
      gld16(Abase + k0 + sOff[j], &As[bf][(w * 4 + j) * 8][0]);
      gld16(Wbase + k0 + sOff[j], &Bs[bf][(w * 4 + j) * 8][0]);
    }
  };

  STAGE(0, 0);
  __syncthreads();
  int buf = 0;
  for (int k0 = 0; k0 < K; k0 += 64) {
    if (k0 + 64 < K) STAGE(k0 + 64, buf ^ 1);   // in flight during compute

    s16x8 a[2][4], b[2][4];
#pragma unroll
    for (int kk = 0; kk < 2; ++kk) {
      const int cg = ((kk * 4 + g) ^ swz) * 8;
#pragma unroll
      for (int mi = 0; mi < 4; ++mi) a[kk][mi] = *(const s16x8*)&As[buf][wr * 64 + mi * 16 + li][cg];
#pragma unroll
      for (int ni = 0; ni < 4; ++ni) b[kk][ni] = *(const s16x8*)&Bs[buf][wc * 64 + ni * 16 + li][cg];
    }
#pragma unroll
    for (int kk = 0; kk < 2; ++kk)
#pragma unroll
      for (int mi = 0; mi < 4; ++mi)
#pragma unroll
        for (int ni = 0; ni < 4; ++ni)
          acc[mi][ni] = __builtin_amdgcn_mfma_f32_16x16x32_bf16(a[kk][mi], b[kk][ni], acc[mi][ni], 0, 0, 0);

    __syncthreads();   // buf read done + stage(k+1) landed
    buf ^= 1;
  }
  epil(acc, wr, wc, g, li);
}

// ---------- fused Q/K/V projection GEMM: blockIdx.z selects tensor ----------
// z=0: V (PERMUTE 2 -> (B,H,E,L)); z=1: K (PERMUTE 1); z=2: Q (PERMUTE 1,
// bias scaled by SCL2E). Requires NON-aliased cv buffers (120MB ws path).
__global__ __launch_bounds__(256) void gemm_qkv(const u16* __restrict__ qa,
                                                const u16* __restrict__ ka,
                                                const u16* __restrict__ va,
                                                const u16* __restrict__ wq,
                                                const u16* __restrict__ wk,
                                                const u16* __restrict__ wv,
                                                const float* __restrict__ bq,
                                                const float* __restrict__ bk,
                                                const float* __restrict__ bv,
                                                u16* __restrict__ qo,
                                                u16* __restrict__ ko,
                                                u16* __restrict__ vo) {
  __shared__ __align__(16) u16 As[2][128][64];
  __shared__ __align__(16) u16 Bs[2][128][64];
  const int z = blockIdx.z;
  const u16* A = z == 0 ? va : (z == 1 ? ka : qa);
  const u16* W = z == 0 ? wv : (z == 1 ? wk : wq);
  const float* bias = z == 0 ? bv : (z == 1 ? bk : bq);
  u16* outp = z == 0 ? vo : (z == 1 ? ko : qo);
  const float bsc = (z == 2) ? SCL2E : 1.0f;
  const int m0 = blockIdx.y * 128, n0 = blockIdx.x * 128;
  const bool perm2 = (z == 0);

  gemm_core(A, W, m0, n0, 1024, As, Bs,
            [&](f32x4 (&acc)[4][4], int wr, int wc, int g, int li) {
#pragma unroll
    for (int mi = 0; mi < 4; ++mi) {
#pragma unroll
      for (int ni = 0; ni < 4; ++ni) {
        const int row = m0 + wr * 64 + mi * 16 + g * 4;
        const int col = n0 + wc * 64 + ni * 16 + li;
        const float bvv = bias[col] * bsc;
        if (perm2) {
          s16x4 pk;
#pragma unroll
          for (int r = 0; r < 4; ++r) pk[r] = (short)f2bf(acc[mi][ni][r] + bvv);
          const int bb = row >> 11, lq = row & (L_ - 1);
          const int hh = col >> 6, e = col & (E_ - 1);
          *(s16x4*)&outp[(((size_t)bb * H_ + hh) * E_ + e) * L_ + lq] = pk;
        } else {
#pragma unroll
          for (int r = 0; r < 4; ++r) {
            const int rr = row + r;
            const int bb = rr >> 11, lq = rr & (L_ - 1);
            const int hh = col >> 6, e = col & (E_ - 1);
            outp[(((size_t)bb * H_ + hh) * L_ + lq) * E_ + e] = f2bf(acc[mi][ni][r] + bvv);
          }
        }
      }
    }
  });
}

// ---------- single GEMM (template PERMUTE), used for Wo and sequential path --
template<int PERMUTE>
__global__ __launch_bounds__(256) void gemm_lds(const u16* __restrict__ A,
                                                const u16* __restrict__ W,
                                                const float* __restrict__ bias,
                                                void* __restrict__ outp,
                                                int M, int N, int K, float bsc)
{
  __shared__ __align__(16) u16 As[2][128][64];
  __shared__ __align__(16) u16 Bs[2][128][64];
  const int m0 = blockIdx.y * 128, n0 = blockIdx.x * 128;

  gemm_core(A, W, m0, n0, K, As, Bs,
            [&](f32x4 (&acc)[4][4], int wr, int wc, int g, int li) {
#pragma unroll
    for (int mi = 0; mi < 4; ++mi) {
#pragma unroll
      for (int ni = 0; ni < 4; ++ni) {
        const int row = m0 + wr * 64 + mi * 16 + g * 4;
        const int col = n0 + wc * 64 + ni * 16 + li;
        const float bv = bias[col] * bsc;
        if (PERMUTE == 2) {
          s16x4 pk;
#pragma unroll
          for (int r = 0; r < 4; ++r) pk[r] = (short)f2bf(acc[mi][ni][r] + bv);
          const int bb = row >> 11, lq = row & (L_ - 1);
          const int hh = col >> 6, e = col & (E_ - 1);
          *(s16x4*)&((u16*)outp)[(((size_t)bb * H_ + hh) * E_ + e) * L_ + lq] = pk;
        } else {
#pragma unroll
          for (int r = 0; r < 4; ++r) {
            const float v = acc[mi][ni][r] + bv;
            const int rr = row + r;
            if (PERMUTE == 1) {
              const int bb = rr >> 11, lq = rr & (L_ - 1);
              const int hh = col >> 6, e = col & (E_ - 1);
              ((u16*)outp)[(((size_t)bb * H_ + hh) * L_ + lq) * E_ + e] = f2bf(v);
            } else {
              ((float*)outp)[(size_t)rr * N + col] = v;
            }
          }
        }
      }
    }
  });
}

// ---------- fallback GEMM (reg-staged, f32 A converted on the fly) ------------
template<int A_BF16, int PERMUTE>
__global__ __launch_bounds__(256) void gemm_bt(const void* __restrict__ Aptr,
                                               const float* __restrict__ W,
                                               const float* __restrict__ bias,
                                               void* __restrict__ outp,
                                               int M, int N, int K, float osc)
{
  __shared__ __align__(16) short As[2][128][40];
  __shared__ __align__(16) short Bs[2][128][40];
  const int tid = threadIdx.x;
  const int m0 = blockIdx.y * 128, n0 = blockIdx.x * 128;
  const int w = tid >> 6, lane = tid & 63, g = lane >> 4, li = lane & 15;
  const int wr = w >> 1, wc = w & 1;

  f32x4 acc[4][4];
#pragma unroll
  for (int i = 0; i < 4; ++i)
#pragma unroll
    for (int j = 0; j < 4; ++j) acc[i][j] = (f32x4){0.f, 0.f, 0.f, 0.f};

  f32x4 ra0[2], ra1[2];
  s16x8 rab[2];
  f32x4 rb0[2], rb1[2];

  auto LOAD = [&](int k0) {
#pragma unroll
    for (int p = 0; p < 2; ++p) {
      const int c = p * 256 + tid, row = c >> 2, kc = (c & 3) * 8;
      if (A_BF16) {
        rab[p] = *(const s16x8*)((const u16*)Aptr + (size_t)(m0 + row) * K + k0 + kc);
      } else {
        const float* ap = (const float*)Aptr + (size_t)(m0 + row) * K + k0 + kc;
        ra0[p] = *(const f32x4*)ap; ra1[p] = *(const f32x4*)(ap + 4);
      }
      const float* wp = W + (size_t)(n0 + row) * K + k0 + kc;
      rb0[p] = *(const f32x4*)wp; rb1[p] = *(const f32x4*)(wp + 4);
    }
  };
  auto WRITE = [&](int buf) {
#pragma unroll
    for (int p = 0; p < 2; ++p) {
      const int c = p * 256 + tid, row = c >> 2, kc = (c & 3) * 8;
      if (A_BF16) {
        *(s16x8*)&As[buf][row][kc] = rab[p];
      } else {
        s16x8 r;
#pragma unroll
        for (int j = 0; j < 4; ++j) { r[j] = (short)f2bf(ra0[p][j]); r[j + 4] = (short)f2bf(ra1[p][j]); }
        *(s16x8*)&As[buf][row][kc] = r;
      }
      s16x8 rb;
#pragma unroll
      for (int j = 0; j < 4; ++j) { rb[j] = (short)f2bf(rb0[p][j]); rb[j + 4] = (short)f2bf(rb1[p][j]); }
      *(s16x8*)&Bs[buf][row][kc] = rb;
    }
  };

  LOAD(0); WRITE(0);
  __syncthreads();
  int cur = 0;
  for (int k0 = 0; k0 < K; k0 += 32) {
    const bool more = (k0 + 32 < K);
    if (more) LOAD(k0 + 32);

    s16x8 a[4], b[4];
#pragma unroll
    for (int mi = 0; mi < 4; ++mi) a[mi] = *(const s16x8*)&As[cur][wr * 64 + mi * 16 + li][g * 8];
#pragma unroll
    for (int ni = 0; ni < 4; ++ni) b[ni] = *(const s16x8*)&Bs[cur][wc * 64 + ni * 16 + li][g * 8];
#pragma unroll
    for (int mi = 0; mi < 4; ++mi)
#pragma unroll
      for (int ni = 0; ni < 4; ++ni)
        acc[mi][ni] = __builtin_amdgcn_mfma_f32_16x16x32_bf16(a[mi], b[ni], acc[mi][ni], 0, 0, 0);

    if (more) { WRITE(cur ^ 1); __syncthreads(); }
    cur ^= 1;
  }

#pragma unroll
  for (int mi = 0; mi < 4; ++mi) {
#pragma unroll
    for (int ni = 0; ni < 4; ++ni) {
      const int row = m0 + wr * 64 + mi * 16 + g * 4;
      const int col = n0 + wc * 64 + ni * 16 + li;
      const float bv = bias[col];
      if (PERMUTE == 2) {
        s16x4 pk;
#pragma unroll
        for (int r = 0; r < 4; ++r) pk[r] = (short)f2bf((acc[mi][ni][r] + bv) * osc);
        const int bb = row >> 11, lq = row & (L_ - 1);
        const int hh = col >> 6, e = col & (E_ - 1);
        *(s16x4*)&((u16*)outp)[(((size_t)bb * H_ + hh) * E_ + e) * L_ + lq] = pk;
      } else {
#pragma unroll
        for (int r = 0; r < 4; ++r) {
          const float v = (acc[mi][ni][r] + bv) * osc;
          const int rr = row + r;
          if (PERMUTE == 1) {
            const int bb = rr >> 11, lq = rr & (L_ - 1);
            const int hh = col >> 6, e = col & (E_ - 1);
            ((u16*)outp)[(((size_t)bb * H_ + hh) * L_ + lq) * E_ + e] = f2bf(v);
          } else {
            ((float*)outp)[(size_t)rr * N + col] = v;
          }
        }
      }
    }
  }
}

// Flash attention, causal (R21 structure — proven 67.5us). Grid: 1024 (1D).
// Block: 512 = 8 waves, QBLK=128 (16 q-rows/wave). XCD-grouped bh; longest
// first. K/V staged in LDS (global_load_lds, dbuf, XOR-swizzled). Lazy
// defer-max; l cross-lane reduce hoisted to epilogue.
__global__ __launch_bounds__(512) void attn_kernel(const u16* __restrict__ qp,
                                                   const u16* __restrict__ kp,
                                                   const u16* __restrict__ vtp,
                                                   u16* __restrict__ op)
{
  __shared__ __align__(16) u16 Ks[2][4096];   // 8KB per buf
  __shared__ __align__(16) u16 Vs[2][4096];
  const int tid = threadIdx.x;
  const unsigned wgid = blockIdx.x;
  const int bh = (wgid & 7) * 8 + ((wgid >> 3) & 7);   // XCD c owns bh in [8c,8c+8)
  const int qb = 15 - (int)(wgid >> 6);                // 128-row q tile, longest first
  const int w = tid >> 6, lane = tid & 63, g = lane >> 4, li = lane & 15;
  const size_t base  = (size_t)bh * L_ * E_;
  const size_t baseT = (size_t)bh * E_ * L_;
  const int bb = bh >> 4, hh = bh & 15;
  const int qbase = qb * 128;
  const int nt = 2 * qb + 2;                  // KV tiles (64 wide) this block needs

  const u16* qr = qp + base + (size_t)(qbase + w * 16 + li) * E_;
  const s16x8 qa0 = *(const s16x8*)(qr + g * 8);
  const s16x8 qa1 = *(const s16x8*)(qr + 32 + g * 8);

  f32x4 o[4];
  float m_run = -1e30f, l_run = 0.f;            // per-lane; l is a PARTIAL sum
#pragma unroll
  for (int nc = 0; nc < 4; ++nc) o[nc] = (f32x4){0.f, 0.f, 0.f, 0.f};

  // staging: 8 waves x (1 K-chunk + 1 V-chunk) of 1KB. Pre-swizzled source.
  int kSrc, vSrc;
  {
    const int s = w * 64 + lane;
    const int row = s >> 3;
    const int c8 = (s & 7) ^ ((row & 3) | (((row >> 3) & 1) << 2));
    kSrc = row * E_ + c8 * 8;
    vSrc = row * L_ + c8 * 8;   // row = e for V^T
  }
  auto stage = [&](int t, int buf) {
    const int kvb = t * 64;
    gld16(kp + base + (size_t)kvb * E_ + kSrc, &Ks[buf][w * 512]);
    gld16(vtp + baseT + kvb + vSrc,            &Vs[buf][w * 512]);
  };

  // fragment read offsets (u16 index into 4096-elem buffer)
  const int swzk = li & 7;
  const int swzv = (li & 3) | (((li >> 3) & 1) << 2);
  int kRd[8], vRd[8];
#pragma unroll
  for (int inst = 0; inst < 4; ++inst) {
    const int bs = (32 * (inst >> 1) + 4 * (inst & 1) + 8 * (li >> 2) + (li & 3)) * 8;
    kRd[inst * 2]     = (bs + (g ^ swzk)) * 8;
    kRd[inst * 2 + 1] = (bs + ((g + 4) ^ swzk)) * 8;
  }
#pragma unroll
  for (int nc = 0; nc < 4; ++nc) {
    const int es = (nc * 16 + li) * 8;
    vRd[nc * 2]     = (es + (g ^ swzv)) * 8;
    vRd[nc * 2 + 1] = (es + ((g + 4) ^ swzv)) * 8;
  }

  stage(0, 0);
  __syncthreads();
  int buf = 0;
  for (int t = 0; t < nt; ++t) {
    const bool more = (t + 1 < nt);
    if (more) stage(t + 1, buf ^ 1);          // async into other buffer

    // QK^T (swapped): p[inst][r] = S^T, k_local = 32*(inst>>1)+8g+4*(inst&1)+r
    s16x8 kf[8];
#pragma unroll
    for (int i = 0; i < 8; ++i) kf[i] = *(const s16x8*)&Ks[buf][kRd[i]];
    f32x4 p[4];
#pragma unroll
    for (int inst = 0; inst < 4; ++inst) {
      f32x4 sf = (f32x4){0.f, 0.f, 0.f, 0.f};
      sf = __builtin_amdgcn_mfma_f32_16x16x32_bf16(kf[inst * 2],     qa0, sf, 0, 0, 0);
      sf = __builtin_amdgcn_mfma_f32_16x16x32_bf16(kf[inst * 2 + 1], qa1, sf, 0, 0, 0);
      p[inst] = sf;   // log2-domain (scale folded into Q)
    }
    if (t >= 2 * qb) {   // diagonal region: causal mask (k > q -> -inf)
      const int qrow = qbase + w * 16 + li;
      const int kvb = t * 64;
#pragma unroll
      for (int inst = 0; inst < 4; ++inst)
#pragma unroll
        for (int r = 0; r < 4; ++r)
          if (kvb + 32 * (inst >> 1) + 8 * g + 4 * (inst & 1) + r > qrow) p[inst][r] = -1e30f;
    }

    s16x8 vf[8];                               // issued before softmax: latency hidden
#pragma unroll
    for (int i = 0; i < 8; ++i) vf[i] = *(const s16x8*)&Vs[buf][vRd[i]];

    // lazy defer-max softmax (log2 domain): common path has NO cross-lane ops
    {
      float m0_ = fmaxf(fmaxf(p[0][0], p[0][1]), fmaxf(p[0][2], p[0][3]));
      float m1_ = fmaxf(fmaxf(p[1][0], p[1][1]), fmaxf(p[1][2], p[1][3]));
      float m2_ = fmaxf(fmaxf(p[2][0], p[2][1]), fmaxf(p[2][2], p[2][3]));
      float m3_ = fmaxf(fmaxf(p[3][0], p[3][1]), fmaxf(p[3][2], p[3][3]));
      const float mx16 = fmaxf(fmaxf(m0_, m1_), fmaxf(m2_, m3_));
      if (__any(mx16 > m_run + 8.0f)) {       // rare after t=0; always at t=0
        float mx = fmaxf(mx16, __shfl_xor(mx16, 16));
        mx = fmaxf(mx, __shfl_xor(mx, 32));
        const float mn = fmaxf(m_run, mx);
        const float alpha = __builtin_amdgcn_exp2f(m_run - mn);
        m_run = mn;
        l_run *= alpha;
#pragma unroll
        for (int nc = 0; nc < 4; ++nc)
#pragma unroll
          for (int r = 0; r < 4; ++r) o[nc][r] *= alpha;
      }
    }
    unsigned pk[8];
    float rs = 0.f;
#pragma unroll
    for (int inst = 0; inst < 4; ++inst) {
      const float e0 = __builtin_amdgcn_exp2f(p[inst][0] - m_run);
      const float e1 = __builtin_amdgcn_exp2f(p[inst][1] - m_run);
      const float e2 = __builtin_amdgcn_exp2f(p[inst][2] - m_run);
      const float e3 = __builtin_amdgcn_exp2f(p[inst][3] - m_run);
      rs += (e0 + e1) + (e2 + e3);
      pk[inst * 2]     = pkbf(e0, e1);
      pk[inst * 2 + 1] = pkbf(e2, e3);
    }
    l_run += rs;                               // per-lane partial; reduced in epilogue

    // O^T += V^T * P^T
    union { s16x8 v; unsigned u[4]; } A0, A1;
    A0.u[0] = pk[0]; A0.u[1] = pk[1]; A0.u[2] = pk[2]; A0.u[3] = pk[3];
    A1.u[0] = pk[4]; A1.u[1] = pk[5]; A1.u[2] = pk[6]; A1.u[3] = pk[7];
#pragma unroll
    for (int nc = 0; nc < 4; ++nc) {
      o[nc] = __builtin_amdgcn_mfma_f32_16x16x32_bf16(vf[nc * 2],     A0.v, o[nc], 0, 0, 0);
      o[nc] = __builtin_amdgcn_mfma_f32_16x16x32_bf16(vf[nc * 2 + 1], A1.v, o[nc], 0, 0, 0);
    }

    if (more) __syncthreads();                 // drains stage(t+1); buf reuse safe
    buf ^= 1;
  }

  // epilogue: final cross-lane l reduce (linear; alphas were uniform per row)
  float lsum = l_run;
  lsum += __shfl_xor(lsum, 16);
  lsum += __shfl_xor(lsum, 32);
  const float inv = 1.0f / lsum;
  u16* orow = op + ((size_t)bb * L_ + qbase + w * 16 + li) * D_ + hh * E_;
#pragma unroll
  for (int nc = 0; nc < 4; ++nc) {
    union { s16x4 v; unsigned u[2]; } P;
    P.u[0] = pkbf(o[nc][0] * inv, o[nc][1] * inv);
    P.u[1] = pkbf(o[nc][2] * inv, o[nc][3] * inv);
    *(s16x4*)&orow[nc * 16 + g * 4] = P.v;
  }
}

extern "C" void kernel_launch(void* const* d_in, const int* in_sizes, int n_in,
                              void* d_out, int out_size, void* d_ws, size_t ws_size,
                              hipStream_t stream) {
  const float* queries = (const float*)d_in[0];
  const float* keys    = (const float*)d_in[1];
  const float* values  = (const float*)d_in[2];
  // d_in[3] = attn_mask: exact causal triu(k=1), applied analytically.
  const float* Wq = (const float*)d_in[4];
  const float* bq = (const float*)d_in[5];
  const float* Wk = (const float*)d_in[6];
  const float* bk = (const float*)d_in[7];
  const float* Wv = (const float*)d_in[8];
  const float* bv = (const float*)d_in[9];
  const float* Wo = (const float*)d_in[10];
  const float* bo = (const float*)d_in[11];

  const size_t MD = (size_t)8192 * 1024;   // activation elems
  const size_t WN = (size_t)1024 * 1024;   // weight elems
  u16* qbuf = (u16*)d_ws;
  u16* kbuf = qbuf + MD;
  u16* vbuf = kbuf + MD;
  u16* abuf = vbuf + MD;

  dim3 blk(256);
  dim3 ggrid(8, 64);

  const size_t need6 = (7 * MD + 4 * WN) * sizeof(u16);   // fused path: 120MB
  const size_t need4 = (4 * MD + 4 * WN) * sizeof(u16);   // sequential: 72MB

  if (ws_size >= need6) {
    // non-aliased cv buffers -> all 3 QKV GEMMs fused in ONE dispatch
    u16* qcv = abuf + MD;
    u16* kcv = qcv + MD;
    u16* vcv = kcv + MD;
    u16* wqb = vcv + MD;
    u16* wkb = wqb + WN;
    u16* wvb = wkb + WN;
    u16* wob = wvb + WN;

    cvtall<<<dim3(14336), blk, 0, stream>>>(queries, keys, values, Wq, Wk, Wv, Wo,
                                            qcv, kcv, vcv, wqb, wkb, wvb, wob);
    gemm_qkv<<<dim3(8, 64, 3), blk, 0, stream>>>(qcv, kcv, vcv, wqb, wkb, wvb,
                                                 bq, bk, bv, qbuf, kbuf, vbuf);
    attn_kernel<<<dim3(1024), dim3(512), 0, stream>>>(qbuf, kbuf, vbuf, abuf);
    gemm_lds<0><<<ggrid, blk, 0, stream>>>(abuf, wob, bo, d_out, 8192, 1024, 1024, 1.0f);
  } else if (ws_size >= need4) {
    // sequential aliased path (R21): consumed in order V -> K -> Q -> attn
    u16* qcv = abuf;
    u16* kcv = qbuf;
    u16* vcv = kbuf;
    u16* wqb = abuf + MD;
    u16* wkb = wqb + WN;
    u16* wvb = wkb + WN;
    u16* wob = wvb + WN;

    cvtall<<<dim3(14336), blk, 0, stream>>>(queries, keys, values, Wq, Wk, Wv, Wo,
                                            qcv, kcv, vcv, wqb, wkb, wvb, wob);
    gemm_lds<2><<<ggrid, blk, 0, stream>>>(vcv, wvb, bv, vbuf, 8192, 1024, 1024, 1.0f);
    gemm_lds<1><<<ggrid, blk, 0, stream>>>(kcv, wkb, bk, kbuf, 8192, 1024, 1024, 1.0f);
    gemm_lds<1><<<ggrid, blk, 0, stream>>>(qcv, wqb, bq, qbuf, 8192, 1024, 1024, SCL2E);
    attn_kernel<<<dim3(1024), dim3(512), 0, stream>>>(qbuf, kbuf, vbuf, abuf);
    gemm_lds<0><<<ggrid, blk, 0, stream>>>(abuf, wob, bo, d_out, 8192, 1024, 1024, 1.0f);
  } else {
    gemm_bt<0, 1><<<ggrid, blk, 0, stream>>>(queries, Wq, bq, qbuf, 8192, 1024, 1024, SCL2E);
    gemm_bt<0, 1><<<ggrid, blk, 0, stream>>>(keys,    Wk, bk, kbuf, 8192, 1024, 1024, 1.0f);
    gemm_bt<0, 2><<<ggrid, blk, 0, stream>>>(values,  Wv, bv, vbuf, 8192, 1024, 1024, 1.0f);
    attn_kernel<<<dim3(1024), dim3(512), 0, stream>>>(qbuf, kbuf, vbuf, abuf);
    gemm_bt<1, 0><<<ggrid, blk, 0, stream>>>(abuf, Wo, bo, d_out, 8192, 1024, 1024, 1.0f);
  }
}

// Round 24
// 173.240 us; speedup vs baseline: 1.1390x; 1.0767x over previous
//
#include <hip/hip_runtime.h>
#include <hip/hip_bf16.h>

typedef float f32x4 __attribute__((ext_vector_type(4)));
typedef short s16x8 __attribute__((ext_vector_type(8)));
typedef short s16x4 __attribute__((ext_vector_type(4)));
typedef unsigned short u16;

#define H_ 16
#define E_ 64
#define D_ 1024
#define L_ 2048
#define SCL2E 0.18033688011f   // (1/sqrt(64)) * log2(e)

__device__ __forceinline__ u16 f2bf(float f) {
  union { float f; unsigned u; } v; v.f = f;
  unsigned u = v.u;
  u += 0x7fffu + ((u >> 16) & 1u);   // round-to-nearest-even
  return (u16)(u >> 16);
}

// pack 2 f32 -> 2 bf16 in one u32 (lo=a, hi=b). NON-volatile: schedulable.
__device__ __forceinline__ unsigned pkbf(float a, float b) {
  unsigned r;
  asm("v_cvt_pk_bf16_f32 %0, %1, %2" : "=v"(r) : "v"(a), "v"(b));
  return r;
}

// async global->LDS, 16B per lane. lds base must be wave-uniform; HW adds lane*16.
__device__ __forceinline__ void gld16(const u16* g, u16* l) {
  __builtin_amdgcn_global_load_lds((const __attribute__((address_space(1))) void*)g,
                                   (__attribute__((address_space(3))) void*)l, 16, 0, 0);
}

// single-launch f32->bf16 convert: 3 activations (4096 blocks each) then
// 4 weights (512 blocks each); Wq pre-scaled by SCL2E (softmax scale fold).
__global__ __launch_bounds__(256) void cvtall(const float* __restrict__ q,
                                              const float* __restrict__ k,
                                              const float* __restrict__ v,
                                              const float* __restrict__ w0,
                                              const float* __restrict__ w1,
                                              const float* __restrict__ w2,
                                              const float* __restrict__ w3,
                                              u16* __restrict__ qd,
                                              u16* __restrict__ kd,
                                              u16* __restrict__ vd,
                                              u16* __restrict__ d0,
                                              u16* __restrict__ d1,
                                              u16* __restrict__ d2,
                                              u16* __restrict__ d3) {
  const int b = blockIdx.x;
  const float* src; u16* dst; float s = 1.0f; size_t off;
  if (b < 12288) {
    const int y = b >> 12, bx = b & 4095;
    src = y == 0 ? q : (y == 1 ? k : v);
    dst = y == 0 ? qd : (y == 1 ? kd : vd);
    off = ((size_t)bx * 256 + threadIdx.x) * 8;
  } else {
    const int b2 = b - 12288, y = b2 >> 9, bx = b2 & 511;
    src = y == 0 ? w0 : (y == 1 ? w1 : (y == 2 ? w2 : w3));
    dst = y == 0 ? d0 : (y == 1 ? d1 : (y == 2 ? d2 : d3));
    if (y == 0) s = SCL2E;
    off = ((size_t)bx * 256 + threadIdx.x) * 8;
  }
  const f32x4 a = *(const f32x4*)(src + off);
  const f32x4 c = *(const f32x4*)(src + off + 4);
  s16x8 r;
#pragma unroll
  for (int j = 0; j < 4; ++j) { r[j] = (short)f2bf(a[j] * s); r[j + 4] = (short)f2bf(c[j] * s); }
  *(s16x8*)(dst + off) = r;
}

// ---------- bf16 GEMM: BK=64, prefetched LDS dbuf, XCD-BIJECTIVE SWIZZLE ----
// Grid: 512 (1D), M=8192 N=1024 K=1024 fixed shape. xcd = wg&7 owns m-tiles
// [8*xcd, 8*xcd+8): per-XCD working set = A-slice 2MB + B 2MB = 4MB = one L2.
// (Old 2D grid put one n-tile per XCD -> every XCD streamed ALL of A: 128MB
// HBM per GEMM. R23's fused-GEMM counters exposed this: 2.6TB/s, 200MB fetch.)
template<int PERMUTE>
__global__ __launch_bounds__(256) void gemm_lds(const u16* __restrict__ A,
                                                const u16* __restrict__ W,
                                                const float* __restrict__ bias,
                                                void* __restrict__ outp,
                                                float bsc)
{
  __shared__ __align__(16) u16 As[2][128][64];   // 32KB
  __shared__ __align__(16) u16 Bs[2][128][64];   // 32KB
  const int K = 1024, N = 1024;
  const unsigned wg = blockIdx.x;
  const int m0 = (int)(((wg & 7) * 8 + ((wg >> 3) & 7)) * 128);
  const int n0 = (int)((wg >> 6) * 128);
  const int tid = threadIdx.x;
  const int w = tid >> 6, lane = tid & 63, g = lane >> 4, li = lane & 15;
  const int wr = w >> 1, wc = w & 1;

  int sOff[4];
#pragma unroll
  for (int j = 0; j < 4; ++j) {
    const int s = (w * 4 + j) * 64 + lane;
    const int row = s >> 3, c8 = s & 7;
    sOff[j] = row * K + ((c8 ^ (row & 7)) * 8);
  }

  f32x4 acc[4][4];
#pragma unroll
  for (int i = 0; i < 4; ++i)
#pragma unroll
    for (int j = 0; j < 4; ++j) acc[i][j] = (f32x4){0.f, 0.f, 0.f, 0.f};

  const u16* Abase = A + (size_t)m0 * K;
  const u16* Wbase = W + (size_t)n0 * K;
  const int swz = li & 7;

  auto STAGE = [&](int k0, int bf) {
#pragma unroll
    for (int j = 0; j < 4; ++j) {
      gld16(Abase + k0 + sOff[j], &As[bf][(w * 4 + j) * 8][0]);
      gld16(Wbase + k0 + sOff[j], &Bs[bf][(w * 4 + j) * 8][0]);
    }
  };

  STAGE(0, 0);
  __syncthreads();
  int buf = 0;
  for (int k0 = 0; k0 < K; k0 += 64) {
    if (k0 + 64 < K) STAGE(k0 + 64, buf ^ 1);   // in flight during compute

    s16x8 a[2][4], b[2][4];
#pragma unroll
    for (int kk = 0; kk < 2; ++kk) {
      const int cg = ((kk * 4 + g) ^ swz) * 8;
#pragma unroll
      for (int mi = 0; mi < 4; ++mi) a[kk][mi] = *(const s16x8*)&As[buf][wr * 64 + mi * 16 + li][cg];
#pragma unroll
      for (int ni = 0; ni < 4; ++ni) b[kk][ni] = *(const s16x8*)&Bs[buf][wc * 64 + ni * 16 + li][cg];
    }
#pragma unroll
    for (int kk = 0; kk < 2; ++kk)
#pragma unroll
      for (int mi = 0; mi < 4; ++mi)
#pragma unroll
        for (int ni = 0; ni < 4; ++ni)
          acc[mi][ni] = __builtin_amdgcn_mfma_f32_16x16x32_bf16(a[kk][mi], b[kk][ni], acc[mi][ni], 0, 0, 0);

    __syncthreads();   // buf read done + stage(k+1) landed
    buf ^= 1;
  }

#pragma unroll
  for (int mi = 0; mi < 4; ++mi) {
#pragma unroll
    for (int ni = 0; ni < 4; ++ni) {
      const int row = m0 + wr * 64 + mi * 16 + g * 4;
      const int col = n0 + wc * 64 + ni * 16 + li;
      const float bv = bias[col] * bsc;
      if (PERMUTE == 2) {
        s16x4 pk;
#pragma unroll
        for (int r = 0; r < 4; ++r) pk[r] = (short)f2bf(acc[mi][ni][r] + bv);
        const int bb = row >> 11, lq = row & (L_ - 1);
        const int hh = col >> 6, e = col & (E_ - 1);
        *(s16x4*)&((u16*)outp)[(((size_t)bb * H_ + hh) * E_ + e) * L_ + lq] = pk;
      } else {
#pragma unroll
        for (int r = 0; r < 4; ++r) {
          const float v = acc[mi][ni][r] + bv;
          const int rr = row + r;
          if (PERMUTE == 1) {
            const int bb = rr >> 11, lq = rr & (L_ - 1);
            const int hh = col >> 6, e = col & (E_ - 1);
            ((u16*)outp)[(((size_t)bb * H_ + hh) * L_ + lq) * E_ + e] = f2bf(v);
          } else {
            ((float*)outp)[(size_t)rr * N + col] = v;
          }
        }
      }
    }
  }
}

// ---------- fallback GEMM (reg-staged, f32 A converted on the fly) ------------
template<int A_BF16, int PERMUTE>
__global__ __launch_bounds__(256) void gemm_bt(const void* __restrict__ Aptr,
                                               const float* __restrict__ W,
                                               const float* __restrict__ bias,
                                               void* __restrict__ outp,
                                               int M, int N, int K, float osc)
{
  __shared__ __align__(16) short As[2][128][40];
  __shared__ __align__(16) short Bs[2][128][40];
  const int tid = threadIdx.x;
  const int m0 = blockIdx.y * 128, n0 = blockIdx.x * 128;
  const int w = tid >> 6, lane = tid & 63, g = lane >> 4, li = lane & 15;
  const int wr = w >> 1, wc = w & 1;

  f32x4 acc[4][4];
#pragma unroll
  for (int i = 0; i < 4; ++i)
#pragma unroll
    for (int j = 0; j < 4; ++j) acc[i][j] = (f32x4){0.f, 0.f, 0.f, 0.f};

  f32x4 ra0[2], ra1[2];
  s16x8 rab[2];
  f32x4 rb0[2], rb1[2];

  auto LOAD = [&](int k0) {
#pragma unroll
    for (int p = 0; p < 2; ++p) {
      const int c = p * 256 + tid, row = c >> 2, kc = (c & 3) * 8;
      if (A_BF16) {
        rab[p] = *(const s16x8*)((const u16*)Aptr + (size_t)(m0 + row) * K + k0 + kc);
      } else {
        const float* ap = (const float*)Aptr + (size_t)(m0 + row) * K + k0 + kc;
        ra0[p] = *(const f32x4*)ap; ra1[p] = *(const f32x4*)(ap + 4);
      }
      const float* wp = W + (size_t)(n0 + row) * K + k0 + kc;
      rb0[p] = *(const f32x4*)wp; rb1[p] = *(const f32x4*)(wp + 4);
    }
  };
  auto WRITE = [&](int buf) {
#pragma unroll
    for (int p = 0; p < 2; ++p) {
      const int c = p * 256 + tid, row = c >> 2, kc = (c & 3) * 8;
      if (A_BF16) {
        *(s16x8*)&As[buf][row][kc] = rab[p];
      } else {
        s16x8 r;
#pragma unroll
        for (int j = 0; j < 4; ++j) { r[j] = (short)f2bf(ra0[p][j]); r[j + 4] = (short)f2bf(ra1[p][j]); }
        *(s16x8*)&As[buf][row][kc] = r;
      }
      s16x8 rb;
#pragma unroll
      for (int j = 0; j < 4; ++j) { rb[j] = (short)f2bf(rb0[p][j]); rb[j + 4] = (short)f2bf(rb1[p][j]); }
      *(s16x8*)&Bs[buf][row][kc] = rb;
    }
  };

  LOAD(0); WRITE(0);
  __syncthreads();
  int cur = 0;
  for (int k0 = 0; k0 < K; k0 += 32) {
    const bool more = (k0 + 32 < K);
    if (more) LOAD(k0 + 32);

    s16x8 a[4], b[4];
#pragma unroll
    for (int mi = 0; mi < 4; ++mi) a[mi] = *(const s16x8*)&As[cur][wr * 64 + mi * 16 + li][g * 8];
#pragma unroll
    for (int ni = 0; ni < 4; ++ni) b[ni] = *(const s16x8*)&Bs[cur][wc * 64 + ni * 16 + li][g * 8];
#pragma unroll
    for (int mi = 0; mi < 4; ++mi)
#pragma unroll
      for (int ni = 0; ni < 4; ++ni)
        acc[mi][ni] = __builtin_amdgcn_mfma_f32_16x16x32_bf16(a[mi], b[ni], acc[mi][ni], 0, 0, 0);

    if (more) { WRITE(cur ^ 1); __syncthreads(); }
    cur ^= 1;
  }

#pragma unroll
  for (int mi = 0; mi < 4; ++mi) {
#pragma unroll
    for (int ni = 0; ni < 4; ++ni) {
      const int row = m0 + wr * 64 + mi * 16 + g * 4;
      const int col = n0 + wc * 64 + ni * 16 + li;
      const float bv = bias[col];
      if (PERMUTE == 2) {
        s16x4 pk;
#pragma unroll
        for (int r = 0; r < 4; ++r) pk[r] = (short)f2bf((acc[mi][ni][r] + bv) * osc);
        const int bb = row >> 11, lq = row & (L_ - 1);
        const int hh = col >> 6, e = col & (E_ - 1);
        *(s16x4*)&((u16*)outp)[(((size_t)bb * H_ + hh) * E_ + e) * L_ + lq] = pk;
      } else {
#pragma unroll
        for (int r = 0; r < 4; ++r) {
          const float v = (acc[mi][ni][r] + bv) * osc;
          const int rr = row + r;
          if (PERMUTE == 1) {
            const int bb = rr >> 11, lq = rr & (L_ - 1);
            const int hh = col >> 6, e = col & (E_ - 1);
            ((u16*)outp)[(((size_t)bb * H_ + hh) * L_ + lq) * E_ + e] = f2bf(v);
          } else {
            ((float*)outp)[(size_t)rr * N + col] = v;
          }
        }
      }
    }
  }
}

// Flash attention, causal (R21 structure, 67.5us) + T5 setprio around MFMA
// clusters. Grid: 1024 (1D). Block: 512 = 8 waves, QBLK=128 (16 q-rows/wave).
// XCD-grouped bh; longest first. K/V staged in LDS (global_load_lds, dbuf,
// XOR-swizzled). Lazy defer-max; l cross-lane reduce hoisted to epilogue.
__global__ __launch_bounds__(512) void attn_kernel(const u16* __restrict__ qp,
                                                   const u16* __restrict__ kp,
                                                   const u16* __restrict__ vtp,
                                                   u16* __restrict__ op)
{
  __shared__ __align__(16) u16 Ks[2][4096];   // 8KB per buf
  __shared__ __align__(16) u16 Vs[2][4096];
  const int tid = threadIdx.x;
  const unsigned wgid = blockIdx.x;
  const int bh = (wgid & 7) * 8 + ((wgid >> 3) & 7);   // XCD c owns bh in [8c,8c+8)
  const int qb = 15 - (int)(wgid >> 6);                // 128-row q tile, longest first
  const int w = tid >> 6, lane = tid & 63, g = lane >> 4, li = lane & 15;
  const size_t base  = (size_t)bh * L_ * E_;
  const size_t baseT = (size_t)bh * E_ * L_;
  const int bb = bh >> 4, hh = bh & 15;
  const int qbase = qb * 128;
  const int nt = 2 * qb + 2;                  // KV tiles (64 wide) this block needs

  const u16* qr = qp + base + (size_t)(qbase + w * 16 + li) * E_;
  const s16x8 qa0 = *(const s16x8*)(qr + g * 8);
  const s16x8 qa1 = *(const s16x8*)(qr + 32 + g * 8);

  f32x4 o[4];
  float m_run = -1e30f, l_run = 0.f;            // per-lane; l is a PARTIAL sum
#pragma unroll
  for (int nc = 0; nc < 4; ++nc) o[nc] = (f32x4){0.f, 0.f, 0.f, 0.f};

  // staging: 8 waves x (1 K-chunk + 1 V-chunk) of 1KB. Pre-swizzled source.
  int kSrc, vSrc;
  {
    const int s = w * 64 + lane;
    const int row = s >> 3;
    const int c8 = (s & 7) ^ ((row & 3) | (((row >> 3) & 1) << 2));
    kSrc = row * E_ + c8 * 8;
    vSrc = row * L_ + c8 * 8;   // row = e for V^T
  }
  auto stage = [&](int t, int buf) {
    const int kvb = t * 64;
    gld16(kp + base + (size_t)kvb * E_ + kSrc, &Ks[buf][w * 512]);
    gld16(vtp + baseT + kvb + vSrc,            &Vs[buf][w * 512]);
  };

  // fragment read offsets (u16 index into 4096-elem buffer)
  const int swzk = li & 7;
  const int swzv = (li & 3) | (((li >> 3) & 1) << 2);
  int kRd[8], vRd[8];
#pragma unroll
  for (int inst = 0; inst < 4; ++inst) {
    const int bs = (32 * (inst >> 1) + 4 * (inst & 1) + 8 * (li >> 2) + (li & 3)) * 8;
    kRd[inst * 2]     = (bs + (g ^ swzk)) * 8;
    kRd[inst * 2 + 1] = (bs + ((g + 4) ^ swzk)) * 8;
  }
#pragma unroll
  for (int nc = 0; nc < 4; ++nc) {
    const int es = (nc * 16 + li) * 8;
    vRd[nc * 2]     = (es + (g ^ swzv)) * 8;
    vRd[nc * 2 + 1] = (es + ((g + 4) ^ swzv)) * 8;
  }

  stage(0, 0);
  __syncthreads();
  int buf = 0;
  for (int t = 0; t < nt; ++t) {
    const bool more = (t + 1 < nt);
    if (more) stage(t + 1, buf ^ 1);          // async into other buffer

    // QK^T (swapped): p[inst][r] = S^T, k_local = 32*(inst>>1)+8g+4*(inst&1)+r
    s16x8 kf[8];
#pragma unroll
    for (int i = 0; i < 8; ++i) kf[i] = *(const s16x8*)&Ks[buf][kRd[i]];
    f32x4 p[4];
    __builtin_amdgcn_s_setprio(1);             // T5: favor MFMA-issuing wave
#pragma unroll
    for (int inst = 0; inst < 4; ++inst) {
      f32x4 sf = (f32x4){0.f, 0.f, 0.f, 0.f};
      sf = __builtin_amdgcn_mfma_f32_16x16x32_bf16(kf[inst * 2],     qa0, sf, 0, 0, 0);
      sf = __builtin_amdgcn_mfma_f32_16x16x32_bf16(kf[inst * 2 + 1], qa1, sf, 0, 0, 0);
      p[inst] = sf;   // log2-domain (scale folded into Q)
    }
    __builtin_amdgcn_s_setprio(0);
    if (t >= 2 * qb) {   // diagonal region: causal mask (k > q -> -inf)
      const int qrow = qbase + w * 16 + li;
      const int kvb = t * 64;
#pragma unroll
      for (int inst = 0; inst < 4; ++inst)
#pragma unroll
        for (int r = 0; r < 4; ++r)
          if (kvb + 32 * (inst >> 1) + 8 * g + 4 * (inst & 1) + r > qrow) p[inst][r] = -1e30f;
    }

    s16x8 vf[8];                               // issued before softmax: latency hidden
#pragma unroll
    for (int i = 0; i < 8; ++i) vf[i] = *(const s16x8*)&Vs[buf][vRd[i]];

    // lazy defer-max softmax (log2 domain): common path has NO cross-lane ops
    {
      float m0_ = fmaxf(fmaxf(p[0][0], p[0][1]), fmaxf(p[0][2], p[0][3]));
      float m1_ = fmaxf(fmaxf(p[1][0], p[1][1]), fmaxf(p[1][2], p[1][3]));
      float m2_ = fmaxf(fmaxf(p[2][0], p[2][1]), fmaxf(p[2][2], p[2][3]));
      float m3_ = fmaxf(fmaxf(p[3][0], p[3][1]), fmaxf(p[3][2], p[3][3]));
      const float mx16 = fmaxf(fmaxf(m0_, m1_), fmaxf(m2_, m3_));
      if (__any(mx16 > m_run + 8.0f)) {       // rare after t=0; always at t=0
        float mx = fmaxf(mx16, __shfl_xor(mx16, 16));
        mx = fmaxf(mx, __shfl_xor(mx, 32));
        const float mn = fmaxf(m_run, mx);
        const float alpha = __builtin_amdgcn_exp2f(m_run - mn);
        m_run = mn;
        l_run *= alpha;
#pragma unroll
        for (int nc = 0; nc < 4; ++nc)
#pragma unroll
          for (int r = 0; r < 4; ++r) o[nc][r] *= alpha;
      }
    }
    unsigned pk[8];
    float rs = 0.f;
#pragma unroll
    for (int inst = 0; inst < 4; ++inst) {
      const float e0 = __builtin_amdgcn_exp2f(p[inst][0] - m_run);
      const float e1 = __builtin_amdgcn_exp2f(p[inst][1] - m_run);
      const float e2 = __builtin_amdgcn_exp2f(p[inst][2] - m_run);
      const float e3 = __builtin_amdgcn_exp2f(p[inst][3] - m_run);
      rs += (e0 + e1) + (e2 + e3);
      pk[inst * 2]     = pkbf(e0, e1);
      pk[inst * 2 + 1] = pkbf(e2, e3);
    }
    l_run += rs;                               // per-lane partial; reduced in epilogue

    // O^T += V^T * P^T
    union { s16x8 v; unsigned u[4]; } A0, A1;
    A0.u[0] = pk[0]; A0.u[1] = pk[1]; A0.u[2] = pk[2]; A0.u[3] = pk[3];
    A1.u[0] = pk[4]; A1.u[1] = pk[5]; A1.u[2] = pk[6]; A1.u[3] = pk[7];
    __builtin_amdgcn_s_setprio(1);             // T5: favor MFMA-issuing wave
#pragma unroll
    for (int nc = 0; nc < 4; ++nc) {
      o[nc] = __builtin_amdgcn_mfma_f32_16x16x32_bf16(vf[nc * 2],     A0.v, o[nc], 0, 0, 0);
      o[nc] = __builtin_amdgcn_mfma_f32_16x16x32_bf16(vf[nc * 2 + 1], A1.v, o[nc], 0, 0, 0);
    }
    __builtin_amdgcn_s_setprio(0);

    if (more) __syncthreads();                 // drains stage(t+1); buf reuse safe
    buf ^= 1;
  }

  // epilogue: final cross-lane l reduce (linear; alphas were uniform per row)
  float lsum = l_run;
  lsum += __shfl_xor(lsum, 16);
  lsum += __shfl_xor(lsum, 32);
  const float inv = 1.0f / lsum;
  u16* orow = op + ((size_t)bb * L_ + qbase + w * 16 + li) * D_ + hh * E_;
#pragma unroll
  for (int nc = 0; nc < 4; ++nc) {
    union { s16x4 v; unsigned u[2]; } P;
    P.u[0] = pkbf(o[nc][0] * inv, o[nc][1] * inv);
    P.u[1] = pkbf(o[nc][2] * inv, o[nc][3] * inv);
    *(s16x4*)&orow[nc * 16 + g * 4] = P.v;
  }
}

extern "C" void kernel_launch(void* const* d_in, const int* in_sizes, int n_in,
                              void* d_out, int out_size, void* d_ws, size_t ws_size,
                              hipStream_t stream) {
  const float* queries = (const float*)d_in[0];
  const float* keys    = (const float*)d_in[1];
  const float* values  = (const float*)d_in[2];
  // d_in[3] = attn_mask: exact causal triu(k=1), applied analytically.
  const float* Wq = (const float*)d_in[4];
  const float* bq = (const float*)d_in[5];
  const float* Wk = (const float*)d_in[6];
  const float* bk = (const float*)d_in[7];
  const float* Wv = (const float*)d_in[8];
  const float* bv = (const float*)d_in[9];
  const float* Wo = (const float*)d_in[10];
  const float* bo = (const float*)d_in[11];

  const size_t MD = (size_t)8192 * 1024;   // activation elems
  const size_t WN = (size_t)1024 * 1024;   // weight elems
  u16* qbuf = (u16*)d_ws;
  u16* kbuf = qbuf + MD;
  u16* vbuf = kbuf + MD;
  u16* abuf = vbuf + MD;

  dim3 blk(256);

  const size_t need = (4 * MD + 4 * WN) * sizeof(u16);   // 72MB
  if (ws_size >= need) {
    // sequential aliased path: cv buffers consumed in order V -> K -> Q -> attn
    u16* qcv = abuf;
    u16* kcv = qbuf;
    u16* vcv = kbuf;
    u16* wqb = abuf + MD;
    u16* wkb = wqb + WN;
    u16* wvb = wkb + WN;
    u16* wob = wvb + WN;

    cvtall<<<dim3(14336), blk, 0, stream>>>(queries, keys, values, Wq, Wk, Wv, Wo,
                                            qcv, kcv, vcv, wqb, wkb, wvb, wob);
    gemm_lds<2><<<dim3(512), blk, 0, stream>>>(vcv, wvb, bv, vbuf, 1.0f);
    gemm_lds<1><<<dim3(512), blk, 0, stream>>>(kcv, wkb, bk, kbuf, 1.0f);
    gemm_lds<1><<<dim3(512), blk, 0, stream>>>(qcv, wqb, bq, qbuf, SCL2E);
    attn_kernel<<<dim3(1024), dim3(512), 0, stream>>>(qbuf, kbuf, vbuf, abuf);
    gemm_lds<0><<<dim3(512), blk, 0, stream>>>(abuf, wob, bo, d_out, 1.0f);
  } else {
    dim3 ggrid(8, 64);
    gemm_bt<0, 1><<<ggrid, blk, 0, stream>>>(queries, Wq, bq, qbuf, 8192, 1024, 1024, SCL2E);
    gemm_bt<0, 1><<<ggrid, blk, 0, stream>>>(keys,    Wk, bk, kbuf, 8192, 1024, 1024, 1.0f);
    gemm_bt<0, 2><<<ggrid, blk, 0, stream>>>(values,  Wv, bv, vbuf, 8192, 1024, 1024, 1.0f);
    attn_kernel<<<dim3(1024), dim3(512), 0, stream>>>(qbuf, kbuf, vbuf, abuf);
    gemm_bt<1, 0><<<ggrid, blk, 0, stream>>>(abuf, Wo, bo, d_out, 8192, 1024, 1024, 1.0f);
  }
}